// Round 1
// baseline (2261.666 us; speedup 1.0000x reference)
//
#include <hip/hip_runtime.h>

#define ALPHA 0.2f

__device__ __forceinline__ float leaky_f(float x) { return x >= 0.0f ? x : ALPHA * x; }

// conv input value: v = 1 - 2*u, where u = FIRST ? leaky(raw) : raw
template<bool FIRST>
__device__ __forceinline__ float vload(float raw) {
  float u = FIRST ? leaky_f(raw) : raw;
  return fmaf(-2.0f, u, 1.0f);
}

// horizontal separable pass for 4 consecutive outputs at (row, 4*x4..4*x4+3)
// h[j] = v[x] + w1*(v[x-1] + v[x+1]), zero padding at x<0 / x>255
template<bool FIRST>
__device__ __forceinline__ void hrow(const float* __restrict__ row, int x4, float w1, float h[4]) {
  const float4 f = *reinterpret_cast<const float4*>(row + (x4 << 2));
  const float v0 = vload<FIRST>(f.x);
  const float v1 = vload<FIRST>(f.y);
  const float v2 = vload<FIRST>(f.z);
  const float v3 = vload<FIRST>(f.w);
  const float vm = (x4 > 0)  ? vload<FIRST>(row[(x4 << 2) - 1]) : 0.0f;
  const float vp = (x4 < 63) ? vload<FIRST>(row[(x4 << 2) + 4]) : 0.0f;
  h[0] = fmaf(w1, vm + v1, v0);
  h[1] = fmaf(w1, v0 + v2, v1);
  h[2] = fmaf(w1, v1 + v3, v2);
  h[3] = fmaf(w1, v2 + vp, v3);
}

// One fixed-point iteration: uout = leaky(o - s * conv1x3x3(1-2*uin))
// Geometry hard-coded: B=16, C=64, H=256, W=256. One thread = 4 consecutive x.
template<bool FIRST>
__global__ __launch_bounds__(256) void iter_k(
    const float* __restrict__ uin,
    const float* __restrict__ o,
    const float* __restrict__ nb_sigma,
    const float* __restrict__ lam,
    float* __restrict__ uout)
{
  const int tid   = blockIdx.x * 256 + threadIdx.x;
  const int x4    = tid & 63;          // W/4 = 64
  const int y     = (tid >> 6) & 255;  // H = 256
  const int plane = tid >> 14;         // b*C + c, 0..1023
  const int c     = plane & 63;

  // per-channel separable-kernel constants (cheap: one expf per thread, memory-bound kernel)
  const float sig  = nb_sigma[c];
  const float sig2 = sig * sig;
  const float w1   = expf(-0.5f / sig2);                       // exp(-1/(2 sigma^2))
  const float s    = lam[0] / (0.62831853071795864769f * sig2); // lam * 1/(0.2*pi*sigma^2)

  const float* src = FIRST ? o : uin;
  const float* pb  = src + ((size_t)plane << 16);

  float ht[4] = {0.f, 0.f, 0.f, 0.f};
  float hm[4];
  float hb[4] = {0.f, 0.f, 0.f, 0.f};
  if (y > 0)   hrow<FIRST>(pb + ((y - 1) << 8), x4, w1, ht);
               hrow<FIRST>(pb + ( y      << 8), x4, w1, hm);
  if (y < 255) hrow<FIRST>(pb + ((y + 1) << 8), x4, w1, hb);

  const size_t off = ((size_t)plane << 16) + (y << 8) + (x4 << 2);
  const float4 of  = *reinterpret_cast<const float4*>(o + off);

  // q' = hm + w1*(ht+hb); u_new = leaky(o - s*q')
  float4 r;
  r.x = leaky_f(fmaf(-s, fmaf(w1, ht[0] + hb[0], hm[0]), of.x));
  r.y = leaky_f(fmaf(-s, fmaf(w1, ht[1] + hb[1], hm[1]), of.y));
  r.z = leaky_f(fmaf(-s, fmaf(w1, ht[2] + hb[2], hm[2]), of.z));
  r.w = leaky_f(fmaf(-s, fmaf(w1, ht[3] + hb[3], hm[3]), of.w));

  *reinterpret_cast<float4*>(uout + off) = r;
}

extern "C" void kernel_launch(void* const* d_in, const int* in_sizes, int n_in,
                              void* d_out, int out_size, void* d_ws, size_t ws_size,
                              hipStream_t stream)
{
  const float* o        = (const float*)d_in[0];
  const float* nb_sigma = (const float*)d_in[1];
  const float* lam      = (const float*)d_in[2];
  float* out = (float*)d_out;
  float* ws  = (float*)d_ws;   // needs 256 MB ping buffer

  const int total4 = 16 * 64 * 256 * 64;  // one thread per float4
  dim3 grid(total4 / 256), block(256);

  // iteration 1: u0 = leaky(o) fused into the load
  iter_k<true><<<grid, block, 0, stream>>>(nullptr, o, nb_sigma, lam, ws);
  // iterations 2..10 ping-pong; even iterations write d_out, so iter 10 lands in d_out
  for (int it = 2; it <= 10; ++it) {
    const float* src = (it & 1) ? out : ws;
    float*       dst = (it & 1) ? ws  : out;
    iter_k<false><<<grid, block, 0, stream>>>(src, o, nb_sigma, lam, dst);
  }
}

// Round 2
// 504.616 us; speedup vs baseline: 4.4820x; 4.4820x over previous
//
#include <hip/hip_runtime.h>

#define ALPHA 0.2f

// lane i <- lane i-1 (shfl_up by 1), lane 0 <- 0   [DPP wave_shr:1, bound_ctrl 0-fill]
__device__ __forceinline__ float dpp_up1(float x) {
  return __builtin_bit_cast(float, __builtin_amdgcn_update_dpp(
      0, __builtin_bit_cast(int, x), 0x138, 0xf, 0xf, true));
}
// lane i <- lane i+1 (shfl_down by 1), lane 63 <- 0 [DPP wave_shl:1]
__device__ __forceinline__ float dpp_dn1(float x) {
  return __builtin_bit_cast(float, __builtin_amdgcn_update_dpp(
      0, __builtin_bit_cast(int, x), 0x130, 0xf, 0xf, true));
}

__device__ __forceinline__ float leaky_f(float x) { return fmaxf(x, ALPHA * x); }

// Fused 10-iteration Jacobi stencil, one wave per (plane, 64-row strip).
// Lane l owns columns 4l..4l+3 (full 256-wide coverage -> no horizontal halo).
// v_k (k=0..9) kept as 3-row rolling register windows; o rows in a 12-deep
// wave-private LDS ring (no barriers). Sweep r = y0-10 .. y0+73 (84 steps).
__global__ __launch_bounds__(64) void pipe_k(
    const float* __restrict__ o,
    const float* __restrict__ nb_sigma,
    const float* __restrict__ lam,
    float* __restrict__ out)
{
  __shared__ float ring[12][256];

  const int lane  = threadIdx.x;      // 0..63
  const int x4    = lane << 2;        // first owned column
  const int bid   = blockIdx.x;       // 0..4095
  const int strip = bid & 3;
  const int plane = bid >> 2;         // b*64 + c
  const int c     = plane & 63;
  const int y0    = strip << 6;
  const int start = y0 - 10;

  const float sig  = nb_sigma[c];
  const float sig2 = sig * sig;
  const float w1   = expf(-0.5f / sig2);                        // per-axis off-center weight
  const float s    = lam[0] / (0.62831853071795864769f * sig2); // lam / (0.2*pi*sigma^2)

  const float* __restrict__ pb = o   + ((size_t)plane << 16);
  float* __restrict__       ob = out + ((size_t)plane << 16);

  // v[k][slot]: 3-row rolling window of iterate k (k=0..9), slot = step mod 3
  float4 v[10][3];
#pragma unroll
  for (int k = 0; k < 10; ++k)
#pragma unroll
    for (int j = 0; j < 3; ++j)
      v[k][j] = make_float4(0.f, 0.f, 0.f, 0.f);

  auto ldrow = [&](int r) -> float4 {
    int rr = r < 0 ? 0 : (r > 255 ? 255 : r);   // clamped (values unused when OOB)
    return *reinterpret_cast<const float4*>(pb + (rr << 8) + x4);
  };

  float4 ocur  = ldrow(start);       // o(row r) for current step
  float4 onext = ldrow(start + 1);   // depth-2 prefetch
  int bslot = 0;                     // ring slot of row r  (= t mod 12)

#pragma unroll 1
  for (int it = 0; it < 28; ++it) {
#pragma unroll
    for (int p = 0; p < 3; ++p) {    // p = t mod 3 (static after unroll)
      const int t = it * 3 + p;
      const int r = start + t;

      float4 onn = ldrow(r + 2);     // prefetch 2 ahead

      // stage o(r) into the ring (read by stages 1..10 over the next 10 steps)
      *reinterpret_cast<float4*>(&ring[bslot][x4]) = ocur;

      // v_0(r) = 1 - 2*leaky(o(r));  rows outside the image are zero-padded
      float4 v0;
      if (r >= 0 && r <= 255) {
        v0.x = fmaf(-2.f, leaky_f(ocur.x), 1.f);
        v0.y = fmaf(-2.f, leaky_f(ocur.y), 1.f);
        v0.z = fmaf(-2.f, leaky_f(ocur.z), 1.f);
        v0.w = fmaf(-2.f, leaky_f(ocur.w), 1.f);
      } else {
        v0 = make_float4(0.f, 0.f, 0.f, 0.f);
      }
      v[0][p] = v0;

#pragma unroll
      for (int k = 1; k <= 10; ++k) {
        const int rho = r - k;                   // target row of this stage
        const float4 a  = v[k-1][(p + 1) % 3];   // row rho-1 (written at t-2)
        const float4 b  = v[k-1][(p + 2) % 3];   // row rho   (written at t-1)
        const float4 cc = v[k-1][p];             // row rho+1 (written this step)

        // vertical separable pass: g = v(rho) + w1*(v(rho-1)+v(rho+1))
        float4 g;
        g.x = fmaf(w1, a.x + cc.x, b.x);
        g.y = fmaf(w1, a.y + cc.y, b.y);
        g.z = fmaf(w1, a.z + cc.z, b.z);
        g.w = fmaf(w1, a.w + cc.w, b.w);

        // horizontal neighbors across lanes (0-fill == image zero padding)
        const float gl = dpp_up1(g.w);   // g(4l-1) from lane l-1
        const float gr = dpp_dn1(g.x);   // g(4l+4) from lane l+1

        // horizontal pass: q = g + w1*(g_left + g_right)
        float4 q;
        q.x = fmaf(w1, gl  + g.y, g.x);
        q.y = fmaf(w1, g.x + g.z, g.y);
        q.z = fmaf(w1, g.y + g.w, g.z);
        q.w = fmaf(w1, g.z + gr , g.w);

        // o(rho) from the LDS ring
        int sk = bslot - k; if (sk < 0) sk += 12;  // uniform -> SALU
        const float4 ok = *reinterpret_cast<const float4*>(&ring[sk][x4]);

        // u = leaky(o - s*q)
        float4 u;
        { float e = fmaf(-s, q.x, ok.x); u.x = leaky_f(e); }
        { float e = fmaf(-s, q.y, ok.y); u.y = leaky_f(e); }
        { float e = fmaf(-s, q.z, ok.z); u.z = leaky_f(e); }
        { float e = fmaf(-s, q.w, ok.w); u.w = leaky_f(e); }

        if (k < 10) {
          // v_k(rho) = 1 - 2u, zero outside the image
          float4 nv;
          if (rho >= 0 && rho <= 255) {
            nv.x = fmaf(-2.f, u.x, 1.f);
            nv.y = fmaf(-2.f, u.y, 1.f);
            nv.z = fmaf(-2.f, u.z, 1.f);
            nv.w = fmaf(-2.f, u.w, 1.f);
          } else {
            nv = make_float4(0.f, 0.f, 0.f, 0.f);
          }
          v[k][p] = nv;
        } else {
          // iterate 10 == final u: store rows owned by this strip
          if (rho >= y0 && rho < y0 + 64) {
            *reinterpret_cast<float4*>(ob + (rho << 8) + x4) = u;
          }
        }
      }

      ocur  = onext;
      onext = onn;
      bslot = (bslot == 11) ? 0 : bslot + 1;
    }
  }
}

extern "C" void kernel_launch(void* const* d_in, const int* in_sizes, int n_in,
                              void* d_out, int out_size, void* d_ws, size_t ws_size,
                              hipStream_t stream)
{
  const float* o        = (const float*)d_in[0];
  const float* nb_sigma = (const float*)d_in[1];
  const float* lam      = (const float*)d_in[2];
  float* out = (float*)d_out;

  // 1024 planes x 4 row-strips, one 64-thread (1-wave) block each
  pipe_k<<<dim3(4096), dim3(64), 0, stream>>>(o, nb_sigma, lam, out);
}

// Round 4
// 488.639 us; speedup vs baseline: 4.6285x; 1.0327x over previous
//
#include <hip/hip_runtime.h>

#define ALPHA 0.2f

// lane i <- lane i-1 (shfl_up by 1), lane 0 <- 0   [DPP wave_shr:1, bound_ctrl 0-fill]
__device__ __forceinline__ float dpp_up1(float x) {
  return __builtin_bit_cast(float, __builtin_amdgcn_update_dpp(
      0, __builtin_bit_cast(int, x), 0x138, 0xf, 0xf, true));
}
// lane i <- lane i+1 (shfl_down by 1), lane 63 <- 0 [DPP wave_shl:1]
__device__ __forceinline__ float dpp_dn1(float x) {
  return __builtin_bit_cast(float, __builtin_amdgcn_update_dpp(
      0, __builtin_bit_cast(int, x), 0x130, 0xf, 0xf, true));
}

__device__ __forceinline__ float leaky_f(float x) { return fmaxf(x, ALPHA * x); }

// Fused 10-iteration Jacobi stencil, one wave per (plane, 128-row strip).
// Lane l owns columns 4l..4l+3 (full 256-wide coverage -> no horizontal halo).
// v_k (k=0..9) kept as 3-row rolling register windows (120 floats — the
// launch_bounds(64,2) budget of 256 VGPRs keeps them in ARCH VGPRs, no
// accvgpr churn); o rows in a 12-deep wave-private LDS ring (no barriers).
// Sweep r = y0-10 .. y0+139 (150 steps, 148 useful).
__global__ __launch_bounds__(64, 2) void pipe_k(
    const float* __restrict__ o,
    const float* __restrict__ nb_sigma,
    const float* __restrict__ lam,
    float* __restrict__ out)
{
  __shared__ float ring[12][256];

  const int lane  = threadIdx.x;      // 0..63
  const int x4    = lane << 2;        // first owned column
  const int bid   = blockIdx.x;       // 0..2047
  const int strip = bid & 1;
  const int plane = bid >> 1;         // b*64 + c
  const int c     = plane & 63;
  const int y0    = strip << 7;       // 0 or 128
  const int start = y0 - 10;

  const float sig  = nb_sigma[c];
  const float sig2 = sig * sig;
  const float w1   = expf(-0.5f / sig2);                        // per-axis off-center weight
  const float s    = lam[0] / (0.62831853071795864769f * sig2); // lam / (0.2*pi*sigma^2)

  const float* __restrict__ pb = o   + ((size_t)plane << 16);
  float* __restrict__       ob = out + ((size_t)plane << 16);

  // v[k][slot]: 3-row rolling window of iterate k (k=0..9), slot = step mod 3
  float4 v[10][3];
#pragma unroll
  for (int k = 0; k < 10; ++k)
#pragma unroll
    for (int j = 0; j < 3; ++j)
      v[k][j] = make_float4(0.f, 0.f, 0.f, 0.f);

  auto ldrow = [&](int r) -> float4 {
    int rr = r < 0 ? 0 : (r > 255 ? 255 : r);   // clamped (values unused when OOB)
    return *reinterpret_cast<const float4*>(pb + (rr << 8) + x4);
  };

  float4 ocur  = ldrow(start);       // o(row r) for current step
  float4 onext = ldrow(start + 1);   // depth-2 prefetch
  int bslot = 0;                     // ring slot of row r  (= t mod 12)

#pragma unroll 1
  for (int it = 0; it < 50; ++it) {
#pragma unroll
    for (int p = 0; p < 3; ++p) {    // p = t mod 3 (static after unroll)
      const int t = it * 3 + p;
      const int r = start + t;

      float4 onn = ldrow(r + 2);     // prefetch 2 ahead

      // stage o(r) into the ring (read by stages 1..10 over the next 10 steps)
      *reinterpret_cast<float4*>(&ring[bslot][x4]) = ocur;

      // v_0(r) = 1 - 2*leaky(o(r));  rows outside the image are zero-padded
      float4 v0;
      if (r >= 0 && r <= 255) {
        v0.x = fmaf(-2.f, leaky_f(ocur.x), 1.f);
        v0.y = fmaf(-2.f, leaky_f(ocur.y), 1.f);
        v0.z = fmaf(-2.f, leaky_f(ocur.z), 1.f);
        v0.w = fmaf(-2.f, leaky_f(ocur.w), 1.f);
      } else {
        v0 = make_float4(0.f, 0.f, 0.f, 0.f);
      }
      v[0][p] = v0;

#pragma unroll
      for (int k = 1; k <= 10; ++k) {
        const int rho = r - k;                   // target row of this stage
        const float4 a  = v[k-1][(p + 1) % 3];   // row rho-1 (written at t-2)
        const float4 b  = v[k-1][(p + 2) % 3];   // row rho   (written at t-1)
        const float4 cc = v[k-1][p];             // row rho+1 (written this step)

        // vertical separable pass: g = v(rho) + w1*(v(rho-1)+v(rho+1))
        float4 g;
        g.x = fmaf(w1, a.x + cc.x, b.x);
        g.y = fmaf(w1, a.y + cc.y, b.y);
        g.z = fmaf(w1, a.z + cc.z, b.z);
        g.w = fmaf(w1, a.w + cc.w, b.w);

        // horizontal neighbors across lanes (0-fill == image zero padding)
        const float gl = dpp_up1(g.w);   // g(4l-1) from lane l-1
        const float gr = dpp_dn1(g.x);   // g(4l+4) from lane l+1

        // horizontal pass: q = g + w1*(g_left + g_right)
        float4 q;
        q.x = fmaf(w1, gl  + g.y, g.x);
        q.y = fmaf(w1, g.x + g.z, g.y);
        q.z = fmaf(w1, g.y + g.w, g.z);
        q.w = fmaf(w1, g.z + gr , g.w);

        // o(rho) from the LDS ring
        int sk = bslot - k; if (sk < 0) sk += 12;  // wave-uniform -> SALU
        const float4 ok = *reinterpret_cast<const float4*>(&ring[sk][x4]);

        // u = leaky(o - s*q)
        float4 u;
        { float e = fmaf(-s, q.x, ok.x); u.x = leaky_f(e); }
        { float e = fmaf(-s, q.y, ok.y); u.y = leaky_f(e); }
        { float e = fmaf(-s, q.z, ok.z); u.z = leaky_f(e); }
        { float e = fmaf(-s, q.w, ok.w); u.w = leaky_f(e); }

        if (k < 10) {
          // v_k(rho) = 1 - 2u, zero outside the image
          float4 nv;
          if (rho >= 0 && rho <= 255) {
            nv.x = fmaf(-2.f, u.x, 1.f);
            nv.y = fmaf(-2.f, u.y, 1.f);
            nv.z = fmaf(-2.f, u.z, 1.f);
            nv.w = fmaf(-2.f, u.w, 1.f);
          } else {
            nv = make_float4(0.f, 0.f, 0.f, 0.f);
          }
          v[k][p] = nv;
        } else {
          // iterate 10 == final u: store rows owned by this strip
          if (rho >= y0 && rho < y0 + 128) {
            __builtin_nontemporal_store(u.x, ob + (rho << 8) + x4 + 0);
            __builtin_nontemporal_store(u.y, ob + (rho << 8) + x4 + 1);
            __builtin_nontemporal_store(u.z, ob + (rho << 8) + x4 + 2);
            __builtin_nontemporal_store(u.w, ob + (rho << 8) + x4 + 3);
          }
        }
      }

      ocur  = onext;
      onext = onn;
      bslot = (bslot == 11) ? 0 : bslot + 1;
    }
  }
}

extern "C" void kernel_launch(void* const* d_in, const int* in_sizes, int n_in,
                              void* d_out, int out_size, void* d_ws, size_t ws_size,
                              hipStream_t stream)
{
  const float* o        = (const float*)d_in[0];
  const float* nb_sigma = (const float*)d_in[1];
  const float* lam      = (const float*)d_in[2];
  float* out = (float*)d_out;

  // 1024 planes x 2 row-strips (128 rows), one 64-thread (1-wave) block each
  pipe_k<<<dim3(2048), dim3(64), 0, stream>>>(o, nb_sigma, lam, out);
}